// Round 8
// baseline (232.973 us; speedup 1.0000x reference)
//
#include <hip/hip_runtime.h>

#define HID 128
#define PTS 32
#define KP  136   // sB k-row stride in bf16 units (128 + 8 pad)
#define FRAGS_PER_W 2048           // 8 mtg * 4 ks * 64 lanes
#define WS_ELEMS (FRAGS_PER_W * 8) // ushorts per (w, hi/lo) plane

typedef float v4f __attribute__((ext_vector_type(4)));
typedef short s8v __attribute__((ext_vector_type(8)));          // 8 bf16 (MFMA A/B frag)

__device__ __forceinline__ unsigned short f2bf(float f) {       // RNE (prep only)
    unsigned u = __builtin_bit_cast(unsigned, f);
    u = (u + 0x7FFFu + ((u >> 16) & 1u)) >> 16;
    return (unsigned short)u;
}
__device__ __forceinline__ float bf2f(unsigned short h) {
    unsigned u = ((unsigned)h) << 16;
    return __builtin_bit_cast(float, u);
}

// --- packed fp32 -> 2x bf16 (RNE), 1 instr on gfx950 ---
#if __has_builtin(__builtin_amdgcn_cvt_pk_bf16_f32)
typedef __bf16 bf16x2 __attribute__((ext_vector_type(2)));
__device__ __forceinline__ unsigned pk2(float f0, float f1) {   // (bf(f1)<<16)|bf(f0)
    return __builtin_bit_cast(unsigned, __builtin_amdgcn_cvt_pk_bf16_f32(f0, f1));
}
#else
__device__ __forceinline__ unsigned pk2(float f0, float f1) {
    unsigned u0 = __builtin_bit_cast(unsigned, f0);
    unsigned u1 = __builtin_bit_cast(unsigned, f1);
    u0 += 0x7FFFu + ((u0 >> 16) & 1u);
    u1 += 0x7FFFu + ((u1 >> 16) & 1u);
    return __builtin_amdgcn_perm(u1, u0, 0x07060302u);
}
#endif

// vectorized tanh: pk-f32 for mul/add/fma, scalar v_exp/v_rcp (no packed trans)
__device__ __forceinline__ v4f tanh4(v4f z) {
#if __has_builtin(__builtin_amdgcn_exp2f)
    v4f zz = z * 2.885390081777927f;    // 2*log2(e)
    v4f e = { __builtin_amdgcn_exp2f(zz[0]), __builtin_amdgcn_exp2f(zz[1]),
              __builtin_amdgcn_exp2f(zz[2]), __builtin_amdgcn_exp2f(zz[3]) };
#else
    v4f zz = z * 2.0f;
    v4f e = { __expf(zz[0]), __expf(zz[1]), __expf(zz[2]), __expf(zz[3]) };
#endif
    v4f d = e + 1.0f;
    v4f r = { __builtin_amdgcn_rcpf(d[0]), __builtin_amdgcn_rcpf(d[1]),
              __builtin_amdgcn_rcpf(d[2]), __builtin_amdgcn_rcpf(d[3]) };
    return 1.0f - 2.0f * r;
}

// One-time: W1/W2 -> RNE-split bf16 A-fragments, frag-linear in d_ws; zero d_out.
// ws plane order: [W1hi][W1lo][W2hi][W2lo]; frag idx r = mtg*256 + ks*64 + lane.
__global__ __launch_bounds__(256) void prep_w_kernel(
    const float* __restrict__ W1, const float* __restrict__ W2,
    unsigned short* __restrict__ ws, float* __restrict__ out)
{
    if (blockIdx.x == 0 && threadIdx.x < 2) out[threadIdx.x] = 0.0f;
    const int t = blockIdx.x * 256 + threadIdx.x;   // 0..4095
    const int w = t >> 11;
    const int r = t & 2047;
    const int mtg = r >> 8;
    const int ks = (r >> 6) & 3;
    const int lane = r & 63;
    const int m = mtg * 16 + (lane & 15);
    const int kb = ks * 32 + (lane >> 4) * 8;
    const float* W = w ? W2 : W1;
    s8v hv, lv;
    #pragma unroll
    for (int i = 0; i < 8; ++i) {
        float f = W[(kb + i) * HID + m];            // A[m][k] = W[k][m]
        unsigned short hh = f2bf(f);
        hv[i] = (short)hh;
        lv[i] = (short)f2bf(f - bf2f(hh));
    }
    *(s8v*)&ws[((size_t)(w * 2 + 0) * FRAGS_PER_W + r) * 8] = hv;
    *(s8v*)&ws[((size_t)(w * 2 + 1) * FRAGS_PER_W + r) * 8] = lv;
}

// Fused interior+boundary. Blocks [0,gi): interior (readout=lap ch 3, no b3);
// blocks [gi, gi+gb): boundary (readout=value ch 0, +b3). All branches block-uniform.
// One block = 32 points, 4 channels (0=val,1=dx,2=dy,3=lap).
// 2-product split-bf16 MFMA: W = whi + wlo (exact to 2^-18, registers),
// activations single RNE bf16 in LDS. Epilogues vectorized (v_pk_fma_f32) with
// v_cvt_pk_bf16_f32 packing. Wave grid: (j-half mh) x (p-half pt).
// C/D layout (m89): col=lane&15, row=quad*4+reg. LDS 34.9 KB -> 4 blocks/CU.
__global__ __launch_bounds__(256, 4) void pinn_mfma_kernel(
    const float* __restrict__ xy_int, const float* __restrict__ f_t,
    const float* __restrict__ xy_bd, const float* __restrict__ g_t,
    const float* __restrict__ W0, const float* __restrict__ b0,
    const float* __restrict__ b1, const float* __restrict__ b2,
    const float* __restrict__ W3, const float* __restrict__ b3,
    const unsigned short* __restrict__ ws, float* __restrict__ out,
    int gi, float scale_int, float scale_bd)
{
    extern __shared__ char smem_raw[];
    unsigned short* sBh = (unsigned short*)smem_raw;     // [4*32][KP] bf16 (RNE)
    float* sRed = (float*)(sBh + 4 * 32 * KP);           // [PTS]

    const bool is_bd = (int)blockIdx.x >= gi;
    const float* __restrict__ xy  = is_bd ? xy_bd : xy_int;
    const float* __restrict__ tgt = is_bd ? g_t : f_t;
    const int rc = is_bd ? 0 : 3;                        // readout channel
    const int pbase = (is_bd ? ((int)blockIdx.x - gi) : (int)blockIdx.x) * PTS;

    const int tid   = threadIdx.x;
    const int lane  = tid & 63;
    const int wave  = tid >> 6;
    const int l15   = lane & 15;
    const int quad  = lane >> 4;
    const int mh    = wave & 1;     // j-half: m-tiles mh*4..mh*4+3
    const int pt    = wave >> 1;    // p-half: cols pt*16..pt*16+15

    // ---- layer 0: 2 -> 128, vector VALU, RNE-bf16 store into sB ----
    {
        const int tj = tid & 31, tp = tid >> 5;
        const int j0 = tj * 4, p0 = tp * 4;
        v4f xv, yv;
        #pragma unroll
        for (int pp = 0; pp < 4; ++pp) {
            const float2 t2 = ((const float2*)xy)[pbase + p0 + pp];
            xv[pp] = t2.x; yv[pp] = t2.y;
        }
        float wx[4], wy[4], bb[4], n2[4];
        #pragma unroll
        for (int jj = 0; jj < 4; ++jj) {
            wx[jj] = W0[j0 + jj];
            wy[jj] = W0[HID + j0 + jj];
            bb[jj] = b0[j0 + jj];
            n2[jj] = -2.0f * fmaf(wx[jj], wx[jj], wy[jj] * wy[jj]);
        }
        v4f chv[4][4];                          // [c][jj], vector over pp
        #pragma unroll
        for (int jj = 0; jj < 4; ++jj) {
            v4f z = xv * wx[jj] + yv * wy[jj] + bb[jj];
            v4f a = tanh4(z);
            v4f t = 1.0f - a * a;
            chv[0][jj] = a;
            chv[1][jj] = t * wx[jj];
            chv[2][jj] = t * wy[jj];
            chv[3][jj] = (a * t) * n2[jj];      // z_lap = 0 at layer 0
        }
        #pragma unroll
        for (int pp = 0; pp < 4; ++pp)
            #pragma unroll
            for (int c = 0; c < 4; ++c) {
                const int row = (c * 32 + p0 + pp) * KP + j0;
                uint2 h = { pk2(chv[c][0][pp], chv[c][1][pp]),
                            pk2(chv[c][2][pp], chv[c][3][pp]) };
                *(uint2*)&sBh[row] = h;
            }
    }
    __syncthreads();

    // ---- hidden layers: D = (Whi + Wlo)(A-op) x Act(B-op), 2-product ----
    #pragma unroll
    for (int L = 0; L < 2; ++L) {
        const unsigned short* wshi = ws + (size_t)L * 2 * WS_ELEMS;
        const unsigned short* wslo = wshi + WS_ELEMS;

        s8v whi[2][4], wlo[2][4];   // [buf][mt] double-buffered per ks stage
        #pragma unroll
        for (int mt = 0; mt < 4; ++mt) {
            const int idx = (mh * 4 + mt) * 256 + lane;   // ks = 0
            whi[0][mt] = *(const s8v*)&wshi[(size_t)idx * 8];
            wlo[0][mt] = *(const s8v*)&wslo[(size_t)idx * 8];
        }

        v4f acc[4][4];   // [mt][c]
        #pragma unroll
        for (int mt = 0; mt < 4; ++mt)
            #pragma unroll
            for (int c = 0; c < 4; ++c)
                acc[mt][c] = (v4f){0.0f, 0.0f, 0.0f, 0.0f};

        #pragma unroll
        for (int ks = 0; ks < 4; ++ks) {
            const int cur = ks & 1, nxt = cur ^ 1;
            if (ks < 3) {   // prefetch next stage from L2 while MFMAs run
                #pragma unroll
                for (int mt = 0; mt < 4; ++mt) {
                    const int idx = (mh * 4 + mt) * 256 + (ks + 1) * 64 + lane;
                    whi[nxt][mt] = *(const s8v*)&wshi[(size_t)idx * 8];
                    wlo[nxt][mt] = *(const s8v*)&wslo[(size_t)idx * 8];
                }
            }
            #pragma unroll
            for (int c = 0; c < 4; ++c) {
                const int rb = ((c * 2 + pt) * 16 + l15) * KP + quad * 8 + ks * 32;
                s8v bh = *(const s8v*)&sBh[rb];
                #pragma unroll
                for (int mt = 0; mt < 4; ++mt)
                    acc[mt][c] = __builtin_amdgcn_mfma_f32_16x16x32_bf16(
                        whi[cur][mt], bh, acc[mt][c], 0, 0, 0);
                #pragma unroll
                for (int mt = 0; mt < 4; ++mt)
                    acc[mt][c] = __builtin_amdgcn_mfma_f32_16x16x32_bf16(
                        wlo[cur][mt], bh, acc[mt][c], 0, 0, 0);
            }
        }
        __syncthreads();            // all waves done reading sB

        const float* __restrict__ bptr = (L == 0) ? b1 : b2;
        #pragma unroll
        for (int mt = 0; mt < 4; ++mt) {
            const int jb = (mh * 4 + mt) * 16 + quad * 4;   // 4 consecutive j
            const int rowb = (pt * 16 + l15) * KP + jb;
            v4f bb = *(const v4f*)&bptr[jb];                // dwordx4
            v4f z = acc[mt][0] + bb;
            v4f a = tanh4(z);
            if (L == 0) {           // need all 4 channels for next layer
                v4f t  = 1.0f - a * a;
                v4f zx = acc[mt][1], zy = acc[mt][2], zl = acc[mt][3];
                v4f s2 = zx * zx + zy * zy;
                v4f c1 = t * zx;
                v4f c2 = t * zy;
                v4f c3 = t * zl + (-2.0f) * ((a * t) * s2);
                uint2 h0 = { pk2(a[0], a[1]),  pk2(a[2], a[3])  };
                uint2 h1 = { pk2(c1[0], c1[1]), pk2(c1[2], c1[3]) };
                uint2 h2 = { pk2(c2[0], c2[1]), pk2(c2[2], c2[3]) };
                uint2 h3 = { pk2(c3[0], c3[1]), pk2(c3[2], c3[3]) };
                *(uint2*)&sBh[rowb]               = h0;
                *(uint2*)&sBh[rowb + 32 * KP]     = h1;
                *(uint2*)&sBh[rowb + 2 * 32 * KP] = h2;
                *(uint2*)&sBh[rowb + 3 * 32 * KP] = h3;
            } else if (is_bd) {     // boundary readout: value only
                uint2 h0 = { pk2(a[0], a[1]), pk2(a[2], a[3]) };
                *(uint2*)&sBh[rowb] = h0;
            } else {                // interior readout: laplacian only
                v4f t  = 1.0f - a * a;
                v4f zx = acc[mt][1], zy = acc[mt][2], zl = acc[mt][3];
                v4f s2 = zx * zx + zy * zy;
                v4f c3 = t * zl + (-2.0f) * ((a * t) * s2);
                uint2 h3 = { pk2(c3[0], c3[1]), pk2(c3[2], c3[3]) };
                *(uint2*)&sBh[rowb + 3 * 32 * KP] = h3;
            }
        }
        __syncthreads();
    }

    // ---- readout: dot with W3 over k, 8 lanes per point ----
    {
        const int p  = tid >> 3;
        const int i  = tid & 7;
        const int k0 = i * 16;
        const int row = (rc * 32 + p) * KP + k0;
        float r = 0.0f;
        #pragma unroll
        for (int h = 0; h < 2; ++h) {
            s8v vh = *(const s8v*)&sBh[row + h * 8];
            #pragma unroll
            for (int t = 0; t < 8; ++t)
                r = fmaf(bf2f((unsigned short)vh[t]), W3[k0 + h * 8 + t], r);
        }
        r += __shfl_xor(r, 1, 64);
        r += __shfl_xor(r, 2, 64);
        r += __shfl_xor(r, 4, 64);
        if (i == 0) {
            float d = r + (is_bd ? b3[0] : 0.0f) - tgt[pbase + p];  // lap kills b3
            sRed[p] = d * d;
        }
    }
    __syncthreads();
    if (tid == 0) {
        float s = 0.0f;
        #pragma unroll
        for (int p = 0; p < PTS; ++p) s += sRed[p];
        atomicAdd(out + (is_bd ? 0 : 1), s * (is_bd ? scale_bd : scale_int));
    }
}

extern "C" void kernel_launch(void* const* d_in, const int* in_sizes, int n_in,
                              void* d_out, int out_size, void* d_ws, size_t ws_size,
                              hipStream_t stream) {
    const float* xy_int = (const float*)d_in[0];
    const float* f      = (const float*)d_in[1];
    const float* xy_bd  = (const float*)d_in[2];
    const float* g      = (const float*)d_in[3];
    const float* W0 = (const float*)d_in[4];
    const float* b0 = (const float*)d_in[5];
    const float* W1 = (const float*)d_in[6];
    const float* b1 = (const float*)d_in[7];
    const float* W2 = (const float*)d_in[8];
    const float* b2 = (const float*)d_in[9];
    const float* W3 = (const float*)d_in[10];
    const float* b3 = (const float*)d_in[11];
    float* out = (float*)d_out;
    unsigned short* ws = (unsigned short*)d_ws;   // needs 256 KB

    const int n_int = in_sizes[0] / 2;   // 262144
    const int n_bd  = in_sizes[2] / 2;   // 16384

    prep_w_kernel<<<16, 256, 0, stream>>>(W1, W2, ws, out);

    const int smem = (4 * 32 * KP) * 2 + PTS * 4;  // 34,944 B -> 4 blocks/CU
    const int gi = n_int / PTS;
    const int gb = n_bd / PTS;

    pinn_mfma_kernel<<<gi + gb, 256, smem, stream>>>(
        xy_int, f, xy_bd, g, W0, b0, b1, b2, W3, b3, ws, out,
        gi, 0.5f / (float)n_int, 0.5f / (float)n_bd);
}